// Round 1
// 309.941 us; speedup vs baseline: 1.5268x; 1.5268x over previous
//
#include <hip/hip_runtime.h>
#include <stdint.h>

#define NTAGS 256
#define BATCH 64
#define SEQ   512
#define NTHREADS 1024   // 16 waves: thread (q=tid>>8, k=tid&255)

#if __has_builtin(__builtin_amdgcn_fdot2_f32_bf16)
#define HAVE_DOT2_BF16 1
typedef __bf16 bf16x2_t __attribute__((ext_vector_type(2)));
#define BCAST(x) __builtin_bit_cast(bf16x2_t, (unsigned int)(x))
#endif

__device__ __forceinline__ float wave_max(float v) {
#pragma unroll
  for (int o = 32; o; o >>= 1) v = fmaxf(v, __shfl_xor(v, o));
  return v;
}
__device__ __forceinline__ float wave_sum(float v) {
#pragma unroll
  for (int o = 32; o; o >>= 1) v += __shfl_xor(v, o);
  return v;
}

__device__ __forceinline__ unsigned int f32_to_bf16_bits(float f) {
  unsigned int u = __float_as_uint(f);
  return (u + 0x7FFFu + ((u >> 16) & 1u)) >> 16;
}

// 32 packed-bf16x2 ET words per thread (proven resident: VGPR=60)
#define ET32(M) \
  M(0) M(1) M(2) M(3) M(4) M(5) M(6) M(7) \
  M(8) M(9) M(10) M(11) M(12) M(13) M(14) M(15) \
  M(16) M(17) M(18) M(19) M(20) M(21) M(22) M(23) \
  M(24) M(25) M(26) M(27) M(28) M(29) M(30) M(31)

#define ET_DECL(p) unsigned int et##p;
// forward: s_k = sum_j a_j E[j,k]; word p = (E[64q+2p][k], E[64q+2p+1][k])
#define ET_INIT(p) \
  et##p = f32_to_bf16_bits(exp2f(trans[(64*q + 2*(p))      * NTAGS + k] * LOG2E)) | \
          (f32_to_bf16_bits(exp2f(trans[(64*q + 2*(p) + 1) * NTAGS + k] * LOG2E)) << 16);
// backward: s_j = sum_k E[j,k] c_k; word p = (E[k][64q+2p], E[k][64q+2p+1])  (k = output j here)
#define ET_INITB(p) \
  et##p = f32_to_bf16_bits(exp2f(trans[k * NTAGS + 64*q + 2*(p)]     * LOG2E)) | \
          (f32_to_bf16_bits(exp2f(trans[k * NTAGS + 64*q + 2*(p) + 1] * LOG2E)) << 16);

// accumulator chain = p % 4 (literal paste)
#define ACC(p) ACC_##p
#define ACC_0  acc0
#define ACC_1  acc1
#define ACC_2  acc2
#define ACC_3  acc3
#define ACC_4  acc0
#define ACC_5  acc1
#define ACC_6  acc2
#define ACC_7  acc3
#define ACC_8  acc0
#define ACC_9  acc1
#define ACC_10 acc2
#define ACC_11 acc3
#define ACC_12 acc0
#define ACC_13 acc1
#define ACC_14 acc2
#define ACC_15 acc3
#define ACC_16 acc0
#define ACC_17 acc1
#define ACC_18 acc2
#define ACC_19 acc3
#define ACC_20 acc0
#define ACC_21 acc1
#define ACC_22 acc2
#define ACC_23 acc3
#define ACC_24 acc0
#define ACC_25 acc1
#define ACC_26 acc2
#define ACC_27 acc3
#define ACC_28 acc0
#define ACC_29 acc1
#define ACC_30 acc2
#define ACC_31 acc3

// hoisted readlanes: 8 independent readlanes, THEN 8 dots consuming SGPRs
#define RL1(p)  const int srg##p = __builtin_amdgcn_readlane((int)w0v, p);
#if HAVE_DOT2_BF16
#define DT1(p)  ACC(p) = __builtin_amdgcn_fdot2_f32_bf16(BCAST(et##p), BCAST(srg##p), ACC(p), false);
#else
#define DT1(p)  { unsigned int u_ = (unsigned int)srg##p; \
  ACC(p) = fmaf(__uint_as_float(u_ << 16),         __uint_as_float(et##p << 16),         ACC(p)); \
  ACC(p) = fmaf(__uint_as_float(u_ & 0xFFFF0000u), __uint_as_float(et##p & 0xFFFF0000u), ACC(p)); }
#endif
#define GRP8(a,b,c,d,e0,f0,g0,h0) \
  RL1(a) RL1(b) RL1(c) RL1(d) RL1(e0) RL1(f0) RL1(g0) RL1(h0) \
  DT1(a) DT1(b) DT1(c) DT1(d) DT1(e0) DT1(f0) DT1(g0) DT1(h0)

// phase A: 256-wide quarter dot into part[], first barrier
#define PHASEA \
    const unsigned int w0v = abuf[(q << 5) + L32];  /* broadcast: 2 lanes/addr */ \
    float acc0 = 0.f, acc1 = 0.f, acc2 = 0.f, acc3 = 0.f; \
    GRP8(0,1,2,3,4,5,6,7) \
    GRP8(8,9,10,11,12,13,14,15) \
    GRP8(16,17,18,19,20,21,22,23) \
    GRP8(24,25,26,27,28,29,30,31) \
    part[q][k] = (acc0 + acc1) + (acc2 + acc3); \
    __syncthreads();

// Forward step (identical to the proven 472us kernel's STEP).
#define STEPF(t, APPLY, MEASURE) { \
    PHASEA \
    if (tid < 256) { \
      const float g = gA;  const int m = mA; \
      gA = gB; mA = mB; \
      const int tp_ = ((t) + 2 < SEQ) ? ((t) + 2) : (SEQ - 1); \
      gB = lg[tp_ * NTAGS + k]; \
      mB = mk[tp_]; \
      const float s = (part[0][k] + part[1][k]) + (part[2][k] + part[3][k]); \
      int e = 0; \
      if (APPLY) { \
        const float4 mx4 = *(const float4*)maxw; \
        const float mx = fmaxf(fmaxf(mx4.x, mx4.y), fmaxf(mx4.z, mx4.w)); \
        e = (int)((__float_as_uint(mx) >> 23) & 0xFF) - 127; \
        esum += e; \
      } \
      const float cand = s * exp2f(fmaf(g, LOG2E, -(float)e)); \
      const float sc = APPLY ? __uint_as_float((unsigned int)(127 - e) << 23) : 1.0f; \
      mya = m ? cand : mya * sc; \
      if (MEASURE) { \
        const float mxv = wave_max(mya); \
        if (lane == 0) maxw[wid] = mxv; \
      } \
      ((unsigned short*)abuf)[k] = (unsigned short)f32_to_bf16_bits(mya); \
    } \
    __syncthreads(); }

// Backward step, iteration t produces c_t from c_{t+1}:
//   b_t = E · c_{t+1};  c_t = e^{g_t} ∘ b_t   (gate m_{t+1}: if 0, b_t = b_{t+1})
// carries gp = g_{t+1} for the masked path: c_t = c_{t+1} ∘ e^{g_t - g_{t+1}}
#define STEPB(t, APPLY, MEASURE) { \
    PHASEA \
    if (tid < 256) { \
      const float g = gA;  const int m = mA; \
      gA = gB; mA = mB; \
      const int tp_ = ((t) >= 2) ? ((t) - 2) : 0; \
      const int tm_ = ((t) >= 1) ? ((t) - 1) : 0; \
      gB = lg[tp_ * NTAGS + k]; \
      mB = mk[tm_]; \
      const float s = (part[0][k] + part[1][k]) + (part[2][k] + part[3][k]); \
      int e = 0; \
      if (APPLY) { \
        const float4 mx4 = *(const float4*)maxw; \
        const float mx = fmaxf(fmaxf(mx4.x, mx4.y), fmaxf(mx4.z, mx4.w)); \
        e = (int)((__float_as_uint(mx) >> 23) & 0xFF) - 127; \
        esum += e; \
      } \
      if (m) myc = s * exp2f(fmaf(g, LOG2E, -(float)e)); \
      else   myc = myc * exp2f(fmaf(g - gp, LOG2E, -(float)e)); \
      gp = g; \
      if (MEASURE) { \
        const float mxv = wave_max(myc); \
        if (lane == 0) maxw[wid] = mxv; \
      } \
      ((unsigned short*)abuf)[k] = (unsigned short)f32_to_bf16_bits(myc); \
    } \
    __syncthreads(); }

// Pass 1: 128 blocks. Even blocks: forward chain a_0..a_255 for batch b.
// Odd blocks: backward chain c_511..c_256 then bare dot -> b_255.
// Both store a 256-float vector (scaled by 2^-esum) + esum to workspace.
__global__ __launch_bounds__(NTHREADS, 4)
void crf_halves(const float* __restrict__ logits,
                const int*   __restrict__ mask,
                const float* __restrict__ trans,
                float* __restrict__ wsA,
                float* __restrict__ wsB,
                int*   __restrict__ wse)
{
  const int b    = blockIdx.x >> 1;
  const int bwd  = blockIdx.x & 1;
  const int tid  = threadIdx.x;
  const int k    = tid & 255;
  const int q    = tid >> 8;        // wave-uniform quarter
  const int lane = tid & 63;
  const int wid  = tid >> 6;        // 0..15
  const int L32  = lane & 31;

  __shared__ unsigned int abuf[NTAGS / 2];   // alpha/c, packed bf16x2
  __shared__ float part[4][NTAGS];           // quarter partials
  __shared__ __align__(16) float maxw[4];    // renorm maxes (waves 0-3 of phase B)

  const float LOG2E = 1.4426950408889634f;

  const float* lg = logits + (size_t)b * SEQ * NTAGS;
  const int*   mk = mask + b * SEQ;

  if (!bwd) {
    // ---------------- forward half: a_0 -> a_255 ----------------
    ET32(ET_DECL)
    ET32(ET_INIT)

    float mya = 0.f;
    int esum = 0;
    if (tid < 256) {
      mya = exp2f(lg[k] * LOG2E);
      ((unsigned short*)abuf)[k] = (unsigned short)f32_to_bf16_bits(mya);
    }
    __syncthreads();

    float gA = 0.f, gB = 0.f;
    int   mA = 1,  mB = 1;
    if (tid < 256) {
      gA = lg[1 * NTAGS + k];
      gB = lg[2 * NTAGS + k];
      mA = mk[1];
      mB = mk[2];
    }

    STEPF(1, 0, 0)
    STEPF(2, 0, 0)
    STEPF(3, 0, 1)
#pragma unroll 1
    for (int tb = 4; tb <= 252; tb += 4) {
      STEPF(tb + 0, 1, 0)
      STEPF(tb + 1, 0, 0)
      STEPF(tb + 2, 0, 0)
      STEPF(tb + 3, 0, 1)
    }
    // mya = a_255[k] * 2^-esum
    if (tid < 256) {
      wsA[b * NTAGS + k] = mya;
      if (tid == 0) wse[2 * b] = esum;
    }
  } else {
    // ---------------- backward half: c_511 -> c_256 -> b_255 ----------------
    ET32(ET_DECL)
    ET32(ET_INITB)

    float myc = 0.f, gp = 0.f;
    int esum = 0;
    if (tid < 256) {
      gp  = lg[(SEQ - 1) * NTAGS + k];   // g_511
      myc = exp2f(gp * LOG2E);           // c_511 = e^{g_511}
      ((unsigned short*)abuf)[k] = (unsigned short)f32_to_bf16_bits(myc);
    }
    __syncthreads();

    float gA = 0.f, gB = 0.f;
    int   mA = 1,  mB = 1;
    if (tid < 256) {
      gA = lg[(SEQ - 2) * NTAGS + k];    // g_510 (for t=510)
      gB = lg[(SEQ - 3) * NTAGS + k];    // g_509
      mA = mk[SEQ - 1];                  // gate m_511 (for t=510)
      mB = mk[SEQ - 2];                  // gate m_510
    }

    STEPB(510, 0, 0)
    STEPB(509, 0, 0)
    STEPB(508, 0, 1)
#pragma unroll 1
    for (int tb = 507; tb >= 259; tb -= 4) {
      STEPB(tb - 0, 1, 0)
      STEPB(tb - 1, 0, 0)
      STEPB(tb - 2, 0, 0)
      STEPB(tb - 3, 0, 1)
    }
    // abuf now holds c_256 (scaled 2^-esum); bare dot -> b_255 (no e^g)
    {
      PHASEA
      if (tid < 256) {
        const float s = (part[0][k] + part[1][k]) + (part[2][k] + part[3][k]);
        wsB[b * NTAGS + k] = s;          // b_255[k] * 2^-esum
        if (tid == 0) wse[2 * b + 1] = esum;
      }
    }
  }
}

// Pass 2 (stream-ordered after pass 1): numerator + den = log(sum a_255∘b_255) + (Ef+Eb)ln2
__global__ __launch_bounds__(256)
void crf_combine(const float* __restrict__ logits,
                 const int*   __restrict__ tags,
                 const int*   __restrict__ mask,
                 const float* __restrict__ trans,
                 const float* __restrict__ wsA,
                 const float* __restrict__ wsB,
                 const int*   __restrict__ wse,
                 float* __restrict__ out)
{
  const int b    = blockIdx.x;
  const int tid  = threadIdx.x;
  const int lane = tid & 63;
  const int wid  = tid >> 6;   // 0..3

  __shared__ float rn[4], rm[4], rp[4];

  const float LN2 = 0.6931471805599453f;
  const float* lg = logits + (size_t)b * SEQ * NTAGS;
  const int*   tg = tags + b * SEQ;
  const int*   mk = mask + b * SEQ;

  float numer = 0.f, msum = 0.f;
  for (int t = tid; t < SEQ; t += 256) {
    int   tag_t = tg[t];
    float m_t   = (float)mk[t];
    msum += m_t;
    if (t < SEQ - 1) {
      numer += lg[t * NTAGS + tag_t] * m_t;
      numer += trans[tag_t * NTAGS + tg[t + 1]] * (float)mk[t + 1];
    }
  }
  numer = wave_sum(numer);
  msum  = wave_sum(msum);
  if (lane == 0) { rn[wid] = numer; rm[wid] = msum; }

  float p = wsA[b * NTAGS + tid] * wsB[b * NTAGS + tid];
  p = wave_sum(p);
  if (lane == 0) rp[wid] = p;
  __syncthreads();

  if (tid == 0) {
    const float numer_tot = (rn[0] + rn[1]) + (rn[2] + rn[3]);
    const float msum_tot  = (rm[0] + rm[1]) + (rm[2] + rm[3]);
    const float psum      = (rp[0] + rp[1]) + (rp[2] + rp[3]);
    const float log_den   = logf(psum) + (float)(wse[2 * b] + wse[2 * b + 1]) * LN2;
    int last_idx = (int)msum_tot - 1;
    if (last_idx < 0) last_idx = 0;
    const int last_tag = tg[last_idx];
    const float score = numer_tot + lg[(SEQ - 1) * NTAGS + last_tag] * (float)mk[SEQ - 1];
    atomicAdd(out, score - log_den);
  }
}

extern "C" void kernel_launch(void* const* d_in, const int* in_sizes, int n_in,
                              void* d_out, int out_size, void* d_ws, size_t ws_size,
                              hipStream_t stream) {
  const float* logits = (const float*)d_in[0];
  const int*   tags   = (const int*)d_in[1];
  const int*   mask   = (const int*)d_in[2];
  const float* trans  = (const float*)d_in[3];
  float* out = (float*)d_out;

  float* ws  = (float*)d_ws;
  float* wsA = ws;                         // [64][256] a_255 * 2^-Ef
  float* wsB = ws + BATCH * NTAGS;         // [64][256] b_255 * 2^-Eb
  int*   wse = (int*)(ws + 2 * BATCH * NTAGS);  // [64][2] esums  (~128.5 KB total)

  hipMemsetAsync(out, 0, sizeof(float), stream);  // harness poisons d_out
  crf_halves<<<dim3(BATCH * 2), dim3(NTHREADS), 0, stream>>>(logits, mask, trans, wsA, wsB, wse);
  crf_combine<<<dim3(BATCH), dim3(256), 0, stream>>>(logits, tags, mask, trans, wsA, wsB, wse, out);
}

// Round 2
// 307.677 us; speedup vs baseline: 1.5380x; 1.0074x over previous
//
#include <hip/hip_runtime.h>
#include <stdint.h>

#define NTAGS 256
#define BATCH 64
#define SEQ   512
#define NTHREADS 256   // 4 waves; thread k owns output tag k; full dot in-thread

#if __has_builtin(__builtin_amdgcn_fdot2_f32_bf16)
#define HAVE_DOT2_BF16 1
typedef __bf16 bf16x2_t __attribute__((ext_vector_type(2)));
#define BCAST(x) __builtin_bit_cast(bf16x2_t, (unsigned int)(x))
#endif

__device__ __forceinline__ float wave_max(float v) {
#pragma unroll
  for (int o = 32; o; o >>= 1) v = fmaxf(v, __shfl_xor(v, o));
  return v;
}
__device__ __forceinline__ float wave_sum(float v) {
#pragma unroll
  for (int o = 32; o; o >>= 1) v += __shfl_xor(v, o);
  return v;
}

__device__ __forceinline__ unsigned int f32_to_bf16_bits(float f) {
  unsigned int u = __float_as_uint(f);
  return (u + 0x7FFFu + ((u >> 16) & 1u)) >> 16;
}

// 128 packed-bf16x2 ET words per thread = full 256-row column of exp(trans)
#define ET128(M) \
  M(0) M(1) M(2) M(3) M(4) M(5) M(6) M(7) M(8) M(9) M(10) M(11) M(12) M(13) M(14) M(15) \
  M(16) M(17) M(18) M(19) M(20) M(21) M(22) M(23) M(24) M(25) M(26) M(27) M(28) M(29) M(30) M(31) \
  M(32) M(33) M(34) M(35) M(36) M(37) M(38) M(39) M(40) M(41) M(42) M(43) M(44) M(45) M(46) M(47) \
  M(48) M(49) M(50) M(51) M(52) M(53) M(54) M(55) M(56) M(57) M(58) M(59) M(60) M(61) M(62) M(63) \
  M(64) M(65) M(66) M(67) M(68) M(69) M(70) M(71) M(72) M(73) M(74) M(75) M(76) M(77) M(78) M(79) \
  M(80) M(81) M(82) M(83) M(84) M(85) M(86) M(87) M(88) M(89) M(90) M(91) M(92) M(93) M(94) M(95) \
  M(96) M(97) M(98) M(99) M(100) M(101) M(102) M(103) M(104) M(105) M(106) M(107) M(108) M(109) M(110) M(111) \
  M(112) M(113) M(114) M(115) M(116) M(117) M(118) M(119) M(120) M(121) M(122) M(123) M(124) M(125) M(126) M(127)

#define ET_DECL(p) unsigned int et##p;
// forward: s_k = sum_j a_j E[j,k]; word p = (E[2p][k], E[2p+1][k])
#define ET_INIT(p) \
  et##p = f32_to_bf16_bits(exp2f(trans[(2*(p))     * NTAGS + k] * LOG2E)) | \
          (f32_to_bf16_bits(exp2f(trans[(2*(p) + 1) * NTAGS + k] * LOG2E)) << 16);
// backward: s_j = sum_k E[j,k] c_k; word p = (E[k][2p], E[k][2p+1])  (thread k = output j)
#define ET_INITB(p) \
  et##p = f32_to_bf16_bits(exp2f(trans[k * NTAGS + 2*(p)]     * LOG2E)) | \
          (f32_to_bf16_bits(exp2f(trans[k * NTAGS + 2*(p) + 1] * LOG2E)) << 16);

// hoisted readlanes: 8 independent readlanes, THEN 8 dots consuming the SGPRs
// (>=8 instructions apart kills the readlane->dot2 wait-state hazard).
// word p lives in lane (p&63) of w0v (p<64) or w1v (p>=64): ternary folds at compile time.
#define RL1(p)  const int srg##p = __builtin_amdgcn_readlane((int)((p) < 64 ? w0v : w1v), (p) & 63);
#if HAVE_DOT2_BF16
#define DT1(p,A)  A = __builtin_amdgcn_fdot2_f32_bf16(BCAST(et##p), BCAST(srg##p), A, false);
#else
#define DT1(p,A)  { unsigned int u_ = (unsigned int)srg##p; \
  A = fmaf(__uint_as_float(u_ << 16),         __uint_as_float(et##p << 16),         A); \
  A = fmaf(__uint_as_float(u_ & 0xFFFF0000u), __uint_as_float(et##p & 0xFFFF0000u), A); }
#endif
#define GRP8(a,b,c,d,e0,f0,g0,h0) \
  RL1(a) RL1(b) RL1(c) RL1(d) RL1(e0) RL1(f0) RL1(g0) RL1(h0) \
  DT1(a,acc0) DT1(b,acc1) DT1(c,acc2) DT1(d,acc3) DT1(e0,acc0) DT1(f0,acc1) DT1(g0,acc2) DT1(h0,acc3)

// full 256-dot, entirely in-thread: 2 LDS broadcast reads + 128 readlane + 128 dot2
#define PHASEA(RB) \
    const unsigned int w0v = abuf[RB][lane]; \
    const unsigned int w1v = abuf[RB][64 + lane]; \
    float acc0 = 0.f, acc1 = 0.f, acc2 = 0.f, acc3 = 0.f; \
    GRP8(0,1,2,3,4,5,6,7) \
    GRP8(8,9,10,11,12,13,14,15) \
    GRP8(16,17,18,19,20,21,22,23) \
    GRP8(24,25,26,27,28,29,30,31) \
    GRP8(32,33,34,35,36,37,38,39) \
    GRP8(40,41,42,43,44,45,46,47) \
    GRP8(48,49,50,51,52,53,54,55) \
    GRP8(56,57,58,59,60,61,62,63) \
    GRP8(64,65,66,67,68,69,70,71) \
    GRP8(72,73,74,75,76,77,78,79) \
    GRP8(80,81,82,83,84,85,86,87) \
    GRP8(88,89,90,91,92,93,94,95) \
    GRP8(96,97,98,99,100,101,102,103) \
    GRP8(104,105,106,107,108,109,110,111) \
    GRP8(112,113,114,115,116,117,118,119) \
    GRP8(120,121,122,123,124,125,126,127)

// One forward step. Double-buffered alpha (RB/WB literal 0/1) -> ONE barrier/step.
// Renorm: max measured at t%4==3, applied at next t%4==0 fused into exp2(g*log2e - e).
#define STEPF(t, RB, WB, APPLY, MEASURE) { \
    PHASEA(RB) \
    const float s = (acc0 + acc1) + (acc2 + acc3); \
    const float g = gA;  const int m = mA; \
    gA = gB; mA = mB; \
    const int tp_ = ((t) + 2 < SEQ) ? ((t) + 2) : (SEQ - 1); \
    gB = lg[tp_ * NTAGS + k]; \
    mB = mk[tp_]; \
    int e = 0; \
    if (APPLY) { \
      const float4 mx4 = *(const float4*)maxw; \
      const float mx = fmaxf(fmaxf(mx4.x, mx4.y), fmaxf(mx4.z, mx4.w)); \
      e = (int)((__float_as_uint(mx) >> 23) & 0xFF) - 127; \
      esum += e; \
    } \
    const float cand = s * exp2f(fmaf(g, LOG2E, -(float)e)); \
    const float sc = APPLY ? __uint_as_float((unsigned int)(127 - e) << 23) : 1.0f; \
    mya = m ? cand : mya * sc; \
    if (MEASURE) { \
      const float mxv = wave_max(mya); \
      if (lane == 0) maxw[wid] = mxv; \
    } \
    ((unsigned short*)abuf[WB])[k] = (unsigned short)f32_to_bf16_bits(mya); \
    __syncthreads(); }

// Backward step, iteration t produces c_t from c_{t+1}:
//   b_t = E · c_{t+1};  c_t = e^{g_t} ∘ b_t   (gate m_{t+1}: if 0, c_t = c_{t+1} ∘ e^{g_t - g_{t+1}})
#define STEPB(t, RB, WB, APPLY, MEASURE) { \
    PHASEA(RB) \
    const float s = (acc0 + acc1) + (acc2 + acc3); \
    const float g = gA;  const int m = mA; \
    gA = gB; mA = mB; \
    const int tp_ = ((t) >= 2) ? ((t) - 2) : 0; \
    const int tm_ = ((t) >= 1) ? ((t) - 1) : 0; \
    gB = lg[tp_ * NTAGS + k]; \
    mB = mk[tm_]; \
    int e = 0; \
    if (APPLY) { \
      const float4 mx4 = *(const float4*)maxw; \
      const float mx = fmaxf(fmaxf(mx4.x, mx4.y), fmaxf(mx4.z, mx4.w)); \
      e = (int)((__float_as_uint(mx) >> 23) & 0xFF) - 127; \
      esum += e; \
    } \
    if (m) myc = s * exp2f(fmaf(g, LOG2E, -(float)e)); \
    else   myc = myc * exp2f(fmaf(g - gp, LOG2E, -(float)e)); \
    gp = g; \
    if (MEASURE) { \
      const float mxv = wave_max(myc); \
      if (lane == 0) maxw[wid] = mxv; \
    } \
    ((unsigned short*)abuf[WB])[k] = (unsigned short)f32_to_bf16_bits(myc); \
    __syncthreads(); }

// Pass 1: 128 blocks x 256 threads. Even blocks: forward chain a_0..a_255.
// Odd blocks: backward chain c_511..c_256, then bare dot -> b_255.
__global__ __launch_bounds__(NTHREADS, 1)
void crf_halves(const float* __restrict__ logits,
                const int*   __restrict__ mask,
                const float* __restrict__ trans,
                float* __restrict__ wsA,
                float* __restrict__ wsB,
                int*   __restrict__ wse)
{
  const int b    = blockIdx.x >> 1;
  const int bwd  = blockIdx.x & 1;
  const int tid  = threadIdx.x;
  const int k    = tid;             // thread owns output tag k
  const int lane = tid & 63;
  const int wid  = tid >> 6;        // 0..3

  __shared__ unsigned int abuf[2][NTAGS / 2];  // alpha/c, packed bf16x2, double-buffered
  __shared__ __align__(16) float maxw[4];      // renorm maxes (one per wave)

  const float LOG2E = 1.4426950408889634f;

  const float* lg = logits + (size_t)b * SEQ * NTAGS;
  const int*   mk = mask + b * SEQ;

  if (!bwd) {
    // ---------------- forward half: a_0 -> a_255 ----------------
    ET128(ET_DECL)
    ET128(ET_INIT)

    float mya = exp2f(lg[k] * LOG2E);
    int esum = 0;
    ((unsigned short*)abuf[0])[k] = (unsigned short)f32_to_bf16_bits(mya);
    __syncthreads();

    float gA = lg[1 * NTAGS + k];
    float gB = lg[2 * NTAGS + k];
    int   mA = mk[1];
    int   mB = mk[2];

    STEPF(1, 0, 1, 0, 0)
    STEPF(2, 1, 0, 0, 0)
    STEPF(3, 0, 1, 0, 1)
#pragma unroll 1
    for (int tb = 4; tb <= 252; tb += 4) {
      STEPF(tb + 0, 1, 0, 1, 0)
      STEPF(tb + 1, 0, 1, 0, 0)
      STEPF(tb + 2, 1, 0, 0, 0)
      STEPF(tb + 3, 0, 1, 0, 1)
    }
    // mya = a_255[k] * 2^-esum
    wsA[b * NTAGS + k] = mya;
    if (tid == 0) wse[2 * b] = esum;
  } else {
    // ---------------- backward half: c_511 -> c_256 -> b_255 ----------------
    ET128(ET_DECL)
    ET128(ET_INITB)

    float gp  = lg[(SEQ - 1) * NTAGS + k];     // g_511
    float myc = exp2f(gp * LOG2E);             // c_511 = e^{g_511}
    int esum = 0;
    ((unsigned short*)abuf[0])[k] = (unsigned short)f32_to_bf16_bits(myc);
    __syncthreads();

    float gA = lg[(SEQ - 2) * NTAGS + k];      // g_510 (for t=510)
    float gB = lg[(SEQ - 3) * NTAGS + k];      // g_509
    int   mA = mk[SEQ - 1];                    // gate m_511 (for t=510)
    int   mB = mk[SEQ - 2];                    // gate m_510

    STEPB(510, 0, 1, 0, 0)
    STEPB(509, 1, 0, 0, 0)
    STEPB(508, 0, 1, 0, 1)
#pragma unroll 1
    for (int tb = 507; tb >= 259; tb -= 4) {
      STEPB(tb - 0, 1, 0, 1, 0)
      STEPB(tb - 1, 0, 1, 0, 0)
      STEPB(tb - 2, 1, 0, 0, 0)
      STEPB(tb - 3, 0, 1, 0, 1)
    }
    // abuf[1] holds c_256 (scaled 2^-esum); bare dot -> b_255 (no e^g)
    {
      PHASEA(1)
      const float s = (acc0 + acc1) + (acc2 + acc3);
      wsB[b * NTAGS + k] = s;                  // b_255[k] * 2^-esum
      if (tid == 0) wse[2 * b + 1] = esum;
    }
  }
}

// Pass 2 (stream-ordered): numerator + den = log(sum a_255∘b_255) + (Ef+Eb)ln2
__global__ __launch_bounds__(256)
void crf_combine(const float* __restrict__ logits,
                 const int*   __restrict__ tags,
                 const int*   __restrict__ mask,
                 const float* __restrict__ trans,
                 const float* __restrict__ wsA,
                 const float* __restrict__ wsB,
                 const int*   __restrict__ wse,
                 float* __restrict__ out)
{
  const int b    = blockIdx.x;
  const int tid  = threadIdx.x;
  const int lane = tid & 63;
  const int wid  = tid >> 6;   // 0..3

  __shared__ float rn[4], rm[4], rp[4];

  const float LN2 = 0.6931471805599453f;
  const float* lg = logits + (size_t)b * SEQ * NTAGS;
  const int*   tg = tags + b * SEQ;
  const int*   mk = mask + b * SEQ;

  float numer = 0.f, msum = 0.f;
  for (int t = tid; t < SEQ; t += 256) {
    int   tag_t = tg[t];
    float m_t   = (float)mk[t];
    msum += m_t;
    if (t < SEQ - 1) {
      numer += lg[t * NTAGS + tag_t] * m_t;
      numer += trans[tag_t * NTAGS + tg[t + 1]] * (float)mk[t + 1];
    }
  }
  numer = wave_sum(numer);
  msum  = wave_sum(msum);
  if (lane == 0) { rn[wid] = numer; rm[wid] = msum; }

  float p = wsA[b * NTAGS + tid] * wsB[b * NTAGS + tid];
  p = wave_sum(p);
  if (lane == 0) rp[wid] = p;
  __syncthreads();

  if (tid == 0) {
    const float numer_tot = (rn[0] + rn[1]) + (rn[2] + rn[3]);
    const float msum_tot  = (rm[0] + rm[1]) + (rm[2] + rm[3]);
    const float psum      = (rp[0] + rp[1]) + (rp[2] + rp[3]);
    const float log_den   = logf(psum) + (float)(wse[2 * b] + wse[2 * b + 1]) * LN2;
    int last_idx = (int)msum_tot - 1;
    if (last_idx < 0) last_idx = 0;
    const int last_tag = tg[last_idx];
    const float score = numer_tot + lg[(SEQ - 1) * NTAGS + last_tag] * (float)mk[SEQ - 1];
    atomicAdd(out, score - log_den);
  }
}

extern "C" void kernel_launch(void* const* d_in, const int* in_sizes, int n_in,
                              void* d_out, int out_size, void* d_ws, size_t ws_size,
                              hipStream_t stream) {
  const float* logits = (const float*)d_in[0];
  const int*   tags   = (const int*)d_in[1];
  const int*   mask   = (const int*)d_in[2];
  const float* trans  = (const float*)d_in[3];
  float* out = (float*)d_out;

  float* ws  = (float*)d_ws;
  float* wsA = ws;                              // [64][256] a_255 * 2^-Ef
  float* wsB = ws + BATCH * NTAGS;              // [64][256] b_255 * 2^-Eb
  int*   wse = (int*)(ws + 2 * BATCH * NTAGS);  // [64][2] esums

  hipMemsetAsync(out, 0, sizeof(float), stream);  // harness poisons d_out
  crf_halves<<<dim3(BATCH * 2), dim3(NTHREADS), 0, stream>>>(logits, mask, trans, wsA, wsB, wse);
  crf_combine<<<dim3(BATCH), dim3(256), 0, stream>>>(logits, tags, mask, trans, wsA, wsB, wse, out);
}